// Round 20
// baseline (199.344 us; speedup 1.0000x reference)
//
#include <hip/hip_runtime.h>
#include <hip/hip_bf16.h>
#include <stdint.h>

#define B_ 2
#define Qn 2048
#define Kn 2048
#define Hn 16
#define Dn 128
#define QT 128     // q rows per block (4 waves x 32)
#define HD (Hn*Dn)

typedef __bf16 bf16x8 __attribute__((ext_vector_type(8)));
typedef __bf16 bf16x4 __attribute__((ext_vector_type(4)));
typedef float f32x4 __attribute__((ext_vector_type(4)));
typedef float f32x16 __attribute__((ext_vector_type(16)));
typedef unsigned short u16x8 __attribute__((ext_vector_type(8)));

union BF8 { __bf16 e[8]; bf16x8 v; };
union U16x8 { unsigned short u[8]; u16x8 v; };

#define SCALE 0.088388347648318447f            // 1/sqrt(128)
#define SCL2  (0.088388347648318447f * 1.4426950408889634f)  // SCALE*log2(e)

#if __has_builtin(__builtin_amdgcn_exp2f)
#define EXP2(x) __builtin_amdgcn_exp2f(x)
#else
#define EXP2(x) exp2f(x)
#endif

__device__ __forceinline__ bf16x4 cvt4(f32x4 a) {
  bf16x4 r;
  r[0] = (__bf16)a[0]; r[1] = (__bf16)a[1];
  r[2] = (__bf16)a[2]; r[3] = (__bf16)a[3];
  return r;
}

// ====================== fused prologue: K + V images ======================
// K image[bh][t128]: [128 rows(keys)][16 slots of 16B], slot' = (slot+row)&15
// V image[bh][t64]:  [128 rows(d)][8 slots of 16B]; slot ds = chunk c=(ds-d)&7,
//   chunk c = keys base(c)+{0..3,8..11}, base(c)=(c>>2)*32+((c>>1)&1)*16+(c&1)*4
__global__ __launch_bounds__(256) void conv_kv(const float* __restrict__ ks,
                                               const float* __restrict__ vs,
                                               const int* __restrict__ vlen,
                                               unsigned short* __restrict__ kws,
                                               unsigned short* __restrict__ vws) {
  __shared__ unsigned short l[64 * 132];
  const int tid = threadIdx.x;
  if (blockIdx.x < 512) {
    const int blk = blockIdx.x;            // bh*16 + t
    const int bh = blk >> 4, t = blk & 15;
    const int b = bh >> 4, h = bh & 15;
    const int nkt = (vlen[b] + 63) >> 6;
    if (t * 2 >= nkt) return;
    const float* src = ks + ((size_t)(b * Kn + t * 128) * Hn + h) * Dn;
    unsigned short* dst = kws + (size_t)blk * 16384;
    #pragma unroll
    for (int i = 0; i < 8; ++i) {
      int idx = i * 256 + tid;
      int row = idx >> 4, sp = idx & 15;
      int slot = (sp - row) & 15;
      const float* s2 = src + (size_t)row * HD + slot * 8;
      f32x4 a0 = *(const f32x4*)s2;
      f32x4 a1 = *(const f32x4*)(s2 + 4);
      U16x8 o;
      *(bf16x4*)&o.u[0] = cvt4(a0);
      *(bf16x4*)&o.u[4] = cvt4(a1);
      *(u16x8*)(dst + (size_t)idx * 8) = o.v;
    }
  } else {
    const int blk = blockIdx.x - 512;      // bh*32 + t
    const int bh = blk >> 5, t = blk & 31;
    const int b = bh >> 4, h = bh & 15;
    const int nkt = (vlen[b] + 63) >> 6;
    if (t >= nkt) return;
    const float* src = vs + ((size_t)(b * Kn + t * 64) * Hn + h) * Dn;
    #pragma unroll
    for (int i = 0; i < 8; ++i) {
      int idx = i * 256 + tid;
      int k = idx >> 5, dc = idx & 31;
      f32x4 a = *(const f32x4*)(src + (size_t)k * HD + dc * 4);
      *(bf16x4*)&l[k * 132 + dc * 4] = cvt4(a);
    }
    __syncthreads();
    unsigned short* dst = vws + (size_t)blk * 8192;
    #pragma unroll
    for (int i = 0; i < 4; ++i) {
      int idx = i * 256 + tid;
      int d = idx >> 3, ds = idx & 7;
      int c = (ds - d) & 7;
      int kb = ((c >> 2) * 32) + (((c >> 1) & 1) * 16) + ((c & 1) * 4);
      U16x8 o;
      #pragma unroll
      for (int j = 0; j < 4; ++j) {
        o.u[j]     = l[(kb + j) * 132 + d];
        o.u[4 + j] = l[(kb + 8 + j) * 132 + d];
      }
      *(u16x8*)(dst + (size_t)idx * 8) = o.v;
    }
  }
}

// ====================== main kernel ======================
__device__ __forceinline__ void dma16(const void* g, void* l) {
  __builtin_amdgcn_global_load_lds((const __attribute__((address_space(1))) void*)g,
                                   (__attribute__((address_space(3))) void*)l, 16, 0, 0);
}
__device__ __forceinline__ void dma_tile(const char* gsrc, char* lds, int tid, int n4k) {
  const int off  = tid * 16;
  const int woff = (tid & 192) * 16;   // wave-uniform LDS base part
  #pragma unroll
  for (int i = 0; i < n4k; ++i)
    dma16(gsrc + i * 4096 + off, lds + i * 4096 + woff);
}

#define WAIT0BAR do { \
  asm volatile("s_waitcnt vmcnt(0)" ::: "memory"); \
  __builtin_amdgcn_s_barrier(); \
  __builtin_amdgcn_sched_barrier(0); } while (0)

// leaves the 8 youngest (zero-stores) in flight; completes the 8 DMA loads
#define WAIT8BAR do { \
  asm volatile("s_waitcnt vmcnt(8)" ::: "memory"); \
  __builtin_amdgcn_s_barrier(); \
  __builtin_amdgcn_sched_barrier(0); } while (0)

// completes the 8 prefetch loads; leaves <=16 attn stores in flight
#define WAIT16BAR do { \
  asm volatile("s_waitcnt vmcnt(16)" ::: "memory"); \
  __builtin_amdgcn_s_barrier(); \
  __builtin_amdgcn_sched_barrier(0); } while (0)

__global__ __launch_bounds__(256, 2) void attn_fwd(
    const float* __restrict__ qs, const int* __restrict__ vlen,
    const char* __restrict__ kimg, const char* __restrict__ vimg,
    float* __restrict__ ctx_out, float* __restrict__ attn_out)
{
  __shared__ __align__(16) char smraw[65536];
  // pass 1: K dbuf 2x16KB @0, V dbuf 2x16KB @32768. pass 2: K dbuf 2x32KB @0.

  const int tid = threadIdx.x, wave = tid >> 6, lane = tid & 63;
  const int l31 = lane & 31, hi = lane >> 5;

  // R18 decode: xcd pins bh-group, batches mixed per XCD
  const int L   = blockIdx.x;
  const int xcd = L & 7;
  const int i5  = L >> 3;
  const int bh  = ((i5 & 3) << 3) + xcd;
  const int qt  = i5 >> 2;
  const int b   = bh >> 4, h = bh & 15;
  const int vl  = vlen[b];
  const int qbw = qt * QT + wave * 32;

  // per-lane ds_read addresses (rotation: row&15 == l31&15 since m*32 = 0 mod 16)
  int vaddrK[8], vaddrV[4];
  #pragma unroll
  for (int s = 0; s < 8; ++s)
    vaddrK[s] = l31 * 256 + (((2 * s + hi + l31) & 15) << 4);
  #pragma unroll
  for (int jj = 0; jj < 4; ++jj)
    vaddrV[jj] = l31 * 128 + ((((hi + 2 * jj) + l31) & 7) << 4);

  // Q fragments pre-scaled by SCALE*log2e
  BF8 qf[8];
  {
    const float* qrow = qs + (((size_t)(b * Qn + qbw + l31)) * Hn + h) * Dn;
    #pragma unroll
    for (int s = 0; s < 8; ++s) {
      int d0 = s * 16 + hi * 8;
      f32x4 a0 = *(const f32x4*)(qrow + d0);
      f32x4 a1 = *(const f32x4*)(qrow + d0 + 4);
      #pragma unroll
      for (int jj = 0; jj < 4; ++jj) {
        qf[s].e[jj]     = (__bf16)(a0[jj] * SCL2);
        qf[s].e[4 + jj] = (__bf16)(a1[jj] * SCL2);
      }
    }
  }

  const char* kimg_bh = kimg + ((size_t)(bh * 16) << 15);
  const char* vimg_bh = vimg + ((size_t)(bh * 32) << 14);

  const int nkt  = (vl + 63) >> 6;      // 64-key tiles (pass 1)
  const int nkt2 = (vl + 127) >> 7;     // 128-key tiles (pass 2)
  const int col0 = nkt * 64;            // attn cols >= col0 are exactly 0
  const int col0_4  = col0 >> 2;        // first zero f32x4 slot in a row
  const int zrounds = (512 - col0_4 + 63) >> 6;   // 64-slot rounds per row (0 if col0==2048)
  const f32x4 z4 = {0.f, 0.f, 0.f, 0.f};
  const bool has_zero = (col0 < Kn);    // block-uniform

  // zero store for inst idx (idempotent via clamping); wave covers its own 32 rows
  #define ZSTORE(idx) do { \
    int row_ = qbw + ((idx) & 31); \
    int rnd_ = (idx) >> 5; \
    rnd_ = (rnd_ > zrounds - 1) ? (zrounds - 1) : rnd_; \
    int c4_ = col0_4 + rnd_ * 64 + lane; \
    c4_ = (c4_ > 511) ? 511 : c4_; \
    *(f32x4*)(attn_out + ((size_t)bh * Qn + row_) * Kn + (size_t)c4_ * 4) = z4; \
  } while (0)

  // ====== pass 1: QK -> exp (unnormalized) -> row sums + PV accumulate ======
  f32x4 rsv = {0.f, 0.f, 0.f, 0.f};
  f32x16 ctxa[4];
  #pragma unroll
  for (int ch = 0; ch < 4; ++ch)
    #pragma unroll
    for (int i = 0; i < 16; ++i) ctxa[ch][i] = 0.f;

  {
    const bool hasb = (vl & 63) != 0;
    dma_tile(kimg_bh, smraw, tid, 4);              // K half-image 0
    dma_tile(vimg_bh, smraw + 32768, tid, 4);      // V tile 0
    WAIT0BAR;
    for (int t = 0; t < nkt; ++t) {
      const int cur = t & 1;
      if (t + 1 < nkt) {
        const int tn = t + 1;
        dma_tile(kimg_bh + ((size_t)(tn >> 1) << 15) + ((size_t)(tn & 1) << 14),
                 smraw + ((cur ^ 1) << 14), tid, 4);
        dma_tile(vimg_bh + ((size_t)tn << 14), smraw + 32768 + ((cur ^ 1) << 14), tid, 4);
      }
      const bool mb = hasb && (t == nkt - 1);
      const char* kb_l = smraw + (cur << 14);
      const char* vb_l = smraw + 32768 + (cur << 14);
      #pragma unroll
      for (int m = 0; m < 2; ++m) {
        f32x16 acc;
        #pragma unroll
        for (int i = 0; i < 16; ++i) acc[i] = 0.f;
        #pragma unroll
        for (int s = 0; s < 8; ++s) {
          BF8 kf; kf.v = *(const bf16x8*)(kb_l + m * 8192 + vaddrK[s]);
          acc = __builtin_amdgcn_mfma_f32_32x32x16_bf16(kf.v, qf[s].v, acc, 0, 0, 0);
        }
        const int kb0 = t * 64 + m * 32;
        BF8 pf0, pf1;
        #pragma unroll
        for (int r4 = 0; r4 < 4; ++r4) {
          #pragma unroll
          for (int rr = 0; rr < 4; ++rr) {
            float e;
            if (!mb) e = EXP2(acc[r4 * 4 + rr]);
            else {
              int key = kb0 + r4 * 8 + hi * 4 + rr;
              e = (key < vl) ? EXP2(acc[r4 * 4 + rr]) : 0.f;
            }
            rsv[rr] += e;
            if (r4 < 2) pf0.e[r4 * 4 + rr] = (__bf16)e;
            else        pf1.e[(r4 - 2) * 4 + rr] = (__bf16)e;
          }
        }
        #pragma unroll
        for (int ch = 0; ch < 4; ++ch) {
          BF8 v0; v0.v = *(const bf16x8*)(vb_l + ch * 4096 + vaddrV[2 * m]);
          ctxa[ch] = __builtin_amdgcn_mfma_f32_32x32x16_bf16(v0.v, pf0.v, ctxa[ch], 0, 0, 0);
          BF8 v1; v1.v = *(const bf16x8*)(vb_l + ch * 4096 + vaddrV[2 * m + 1]);
          ctxa[ch] = __builtin_amdgcn_mfma_f32_32x32x16_bf16(v1.v, pf1.v, ctxa[ch], 0, 0, 0);
        }
      }
      // interleaved zero-fill: exactly 8 stores/tile (uniform), counted barrier
      if (has_zero) {
        const int zb = t * 8;
        #pragma unroll
        for (int zi = 0; zi < 8; ++zi) ZSTORE(zb + zi);
        WAIT8BAR;    // completes the 8 DMA loads (older); zero-stores stay in flight
      } else {
        WAIT0BAR;    // uniform branch: all waves take the same side
      }
    }
  }
  float rs = (rsv[0] + rsv[1]) + (rsv[2] + rsv[3]);
  rs += __shfl_xor(rs, 32);
  const float inv = 1.0f / rs;   // row sum for q-row (qbw + l31)

  // remainder of zero-fill (small-vl blocks): fire-and-forget, drained by pass 2's first barrier
  if (has_zero) {
    for (int idx = nkt * 8; idx < 32 * zrounds; ++idx) ZSTORE(idx);
  }

  // ====== pass 2: lean QK -> exp*inv -> attn store (KT=128, K-only dbuf) ======
  {
    const bool hasb2 = (vl & 127) != 0;
    dma_tile(kimg_bh, smraw, tid, 8);
    WAIT0BAR;                            // drains zero remainder + initial dma (once)
    float* rowp = attn_out + ((size_t)bh * Qn + qbw + l31) * Kn;
    for (int t = 0; t < nkt2; ++t) {
      const int cur = t & 1;
      if (t + 1 < nkt2)
        dma_tile(kimg_bh + ((size_t)(t + 1) << 15), smraw + ((cur ^ 1) << 15), tid, 8);
      const bool mb = hasb2 && (t == nkt2 - 1);
      const char* kb_l = smraw + (cur << 15);
      #pragma unroll
      for (int m = 0; m < 4; ++m) {
        f32x16 acc;
        #pragma unroll
        for (int i = 0; i < 16; ++i) acc[i] = 0.f;
        #pragma unroll
        for (int s = 0; s < 8; ++s) {
          BF8 kf; kf.v = *(const bf16x8*)(kb_l + m * 8192 + vaddrK[s]);
          acc = __builtin_amdgcn_mfma_f32_32x32x16_bf16(kf.v, qf[s].v, acc, 0, 0, 0);
        }
        const int kb0 = t * 128 + m * 32;
        #pragma unroll
        for (int r4 = 0; r4 < 4; ++r4) {
          f32x4 p;
          if (!mb) {
            #pragma unroll
            for (int rr = 0; rr < 4; ++rr) p[rr] = EXP2(acc[r4 * 4 + rr]) * inv;
          } else {
            #pragma unroll
            for (int rr = 0; rr < 4; ++rr) {
              int key = kb0 + r4 * 8 + hi * 4 + rr;
              p[rr] = (key < vl) ? EXP2(acc[r4 * 4 + rr]) * inv : 0.f;
            }
          }
          *(f32x4*)(rowp + kb0 + r4 * 8 + hi * 4) = p;
        }
      }
      WAIT16BAR;   // 8 prefetch loads complete; attn stores stay in flight
    }
  }

  // epilogue: ctx[q=l31][d = ch*32 + r4*8 + hi*4 + rr] = ctxa * inv
  float* cp = ctx_out + (((size_t)(b * Qn + qbw + l31)) * Hn + h) * Dn;
  #pragma unroll
  for (int ch = 0; ch < 4; ++ch)
    #pragma unroll
    for (int r4 = 0; r4 < 4; ++r4) {
      f32x4 o;
      #pragma unroll
      for (int rr = 0; rr < 4; ++rr) o[rr] = ctxa[ch][r4 * 4 + rr] * inv;
      *(f32x4*)(cp + ch * 32 + r4 * 8 + hi * 4) = o;
    }
  #undef ZSTORE
}

// ====================== fallback (R13-based, proven): used only if ws < 32MB ======================
#define KT 64
#define KT1 128
#define KROW 132
#define VROW 72
struct SMp2f { unsigned short K[2][KT][KROW]; unsigned short V[2][Dn][VROW]; };
union SMuf { SMp2f p2; unsigned short K1[2][KT1][KROW]; };

__device__ __forceinline__ void bar_lgkm() {
  asm volatile("s_waitcnt lgkmcnt(0)" ::: "memory");
  __builtin_amdgcn_s_barrier();
  __builtin_amdgcn_sched_barrier(0);
}
__device__ __forceinline__ void fb_stage_k64(const float* kb, unsigned short (*dst)[KROW], int tid) {
  #pragma unroll
  for (int ii = 0; ii < 8; ++ii) {
    int chunk = ii * 256 + tid;
    int row = chunk >> 5, cv = chunk & 31;
    f32x4 a = *(const f32x4*)(kb + (size_t)row * HD + cv * 4);
    *(bf16x4*)&dst[row][cv * 4] = cvt4(a);
  }
}
__device__ __forceinline__ void fb_stage_k128(const float* kb, unsigned short (*dst)[KROW], int tid) {
  #pragma unroll
  for (int ii = 0; ii < 16; ++ii) {
    int chunk = ii * 256 + tid;
    int row = chunk >> 5, cv = chunk & 31;
    f32x4 a = *(const f32x4*)(kb + (size_t)row * HD + cv * 4);
    *(bf16x4*)&dst[row][cv * 4] = cvt4(a);
  }
}
__device__ __forceinline__ void fb_stage_v64(const float* vb, unsigned short (*dst)[VROW], int tid) {
  int d = tid & 127, t0 = tid >> 7;
  const float* colp = vb + d;
  #pragma unroll
  for (int rr = 0; rr < 4; ++rr) {
    int idx = rr * 2 + t0;
    int base = (idx >> 2) * 32 + ((idx >> 1) & 1) * 16 + (idx & 1) * 4;
    BF8 t;
    #pragma unroll
    for (int jj = 0; jj < 4; ++jj) {
      t.e[jj]     = (__bf16)colp[(size_t)(base + jj) * HD];
      t.e[4 + jj] = (__bf16)colp[(size_t)(base + 8 + jj) * HD];
    }
    *(bf16x8*)&dst[d][idx * 8] = t.v;
  }
}
__global__ __launch_bounds__(256, 2) void attn_fwd_fb(
    const float* __restrict__ qs, const float* __restrict__ ks,
    const float* __restrict__ vs, const int* __restrict__ vlen,
    float* __restrict__ ctx_out, float* __restrict__ attn_out)
{
  __shared__ __align__(16) SMuf sm;
  const int tid = threadIdx.x, wave = tid >> 6, lane = tid & 63;
  const int l31 = lane & 31, hi = lane >> 5;
  const int L = blockIdx.x, xcd = L & 7, i5 = L >> 3;
  const int bh = ((i5 & 3) << 3) + xcd, qt = i5 >> 2;
  const int b = bh >> 4, h = bh & 15;
  const int vl = vlen[b];
  const int qbw = qt * QT + wave * 32;
  BF8 qf[8];
  {
    const float* qrow = qs + (((size_t)(b * Qn + qbw + l31)) * Hn + h) * Dn;
    #pragma unroll
    for (int s = 0; s < 8; ++s) {
      int d0 = s * 16 + hi * 8;
      f32x4 a0 = *(const f32x4*)(qrow + d0);
      f32x4 a1 = *(const f32x4*)(qrow + d0 + 4);
      #pragma unroll
      for (int jj = 0; jj < 4; ++jj) {
        qf[s].e[jj] = (__bf16)(a0[jj] * SCL2);
        qf[s].e[4 + jj] = (__bf16)(a1[jj] * SCL2);
      }
    }
  }
  const float* kbase = ks + ((size_t)b * Kn * Hn + h) * Dn;
  const float* vbase = vs + ((size_t)b * Kn * Hn + h) * Dn;
  f32x4 rsv = {0.f, 0.f, 0.f, 0.f};
  {
    const int nkt1 = (vl + KT1 - 1) / KT1;
    const bool hasb1 = (vl & (KT1 - 1)) != 0;
    fb_stage_k128(kbase, sm.K1[0], tid);
    bar_lgkm();
    for (int t = 0; t < nkt1; ++t) {
      const int cur = t & 1;
      if (t + 1 < nkt1) fb_stage_k128(kbase + (size_t)(t + 1) * KT1 * HD, sm.K1[cur ^ 1], tid);
      const bool mb = hasb1 && (t == nkt1 - 1);
      #pragma unroll
      for (int m = 0; m < 4; ++m) {
        f32x16 acc;
        #pragma unroll
        for (int i = 0; i < 16; ++i) acc[i] = 0.f;
        #pragma unroll
        for (int s = 0; s < 8; ++s) {
          BF8 kf; kf.v = *(const bf16x8*)&sm.K1[cur][m * 32 + l31][s * 16 + hi * 8];
          acc = __builtin_amdgcn_mfma_f32_32x32x16_bf16(kf.v, qf[s].v, acc, 0, 0, 0);
        }
        if (!mb) {
          #pragma unroll
          for (int reg = 0; reg < 16; ++reg) rsv[reg & 3] += EXP2(acc[reg]);
        } else {
          const int kb0 = t * KT1 + m * 32 + hi * 4;
          #pragma unroll
          for (int reg = 0; reg < 16; ++reg) {
            int key = kb0 + (reg & 3) + 8 * (reg >> 2);
            rsv[reg & 3] += (key < vl) ? EXP2(acc[reg]) : 0.f;
          }
        }
      }
      bar_lgkm();
    }
  }
  float rs = (rsv[0] + rsv[1]) + (rsv[2] + rsv[3]);
  rs += __shfl_xor(rs, 32);
  const float inv = 1.0f / rs;
  f32x16 ctxa[4];
  #pragma unroll
  for (int ch = 0; ch < 4; ++ch)
    #pragma unroll
    for (int i = 0; i < 16; ++i) ctxa[ch][i] = 0.f;
  const int nkt = (vl + KT - 1) / KT;
  const bool hasb2 = (vl & (KT - 1)) != 0;
  fb_stage_k64(kbase, sm.p2.K[0], tid);
  fb_stage_v64(vbase, sm.p2.V[0], tid);
  bar_lgkm();
  float* rowp = attn_out + ((size_t)bh * Qn + qbw + l31) * Kn;
  for (int t = 0; t < nkt; ++t) {
    const int cur = t & 1;
    if (t + 1 < nkt) {
      fb_stage_k64(kbase + (size_t)(t + 1) * KT * HD, sm.p2.K[cur ^ 1], tid);
      fb_stage_v64(vbase + (size_t)(t + 1) * KT * HD, sm.p2.V[cur ^ 1], tid);
    }
    const bool mb = hasb2 && (t == nkt - 1);
    #pragma unroll
    for (int m = 0; m < 2; ++m) {
      f32x16 acc;
      #pragma unroll
      for (int i = 0; i < 16; ++i) acc[i] = 0.f;
      #pragma unroll
      for (int s = 0; s < 8; ++s) {
        BF8 kf; kf.v = *(const bf16x8*)&sm.p2.K[cur][m * 32 + l31][s * 16 + hi * 8];
        acc = __builtin_amdgcn_mfma_f32_32x32x16_bf16(kf.v, qf[s].v, acc, 0, 0, 0);
      }
      const int kb0 = t * KT + m * 32;
      BF8 pf0, pf1;
      #pragma unroll
      for (int r4 = 0; r4 < 4; ++r4) {
        f32x4 p;
        if (!mb) {
          #pragma unroll
          for (int rr = 0; rr < 4; ++rr) p[rr] = EXP2(acc[r4 * 4 + rr]) * inv;
        } else {
          #pragma unroll
          for (int rr = 0; rr < 4; ++rr) {
            int key = kb0 + r4 * 8 + hi * 4 + rr;
            p[rr] = (key < vl) ? EXP2(acc[r4 * 4 + rr]) * inv : 0.f;
          }
        }
        #pragma unroll
        for (int rr = 0; rr < 4; ++rr) {
          if (r4 < 2) pf0.e[r4 * 4 + rr] = (__bf16)p[rr];
          else        pf1.e[(r4 - 2) * 4 + rr] = (__bf16)p[rr];
        }
        *(f32x4*)(rowp + kb0 + r4 * 8 + hi * 4) = p;
      }
      #pragma unroll
      for (int ch = 0; ch < 4; ++ch) {
        BF8 v0; v0.v = *(const bf16x8*)&sm.p2.V[cur][ch * 32 + l31][(m * 4 + hi) * 8];
        ctxa[ch] = __builtin_amdgcn_mfma_f32_32x32x16_bf16(v0.v, pf0.v, ctxa[ch], 0, 0, 0);
        BF8 v1; v1.v = *(const bf16x8*)&sm.p2.V[cur][ch * 32 + l31][(m * 4 + 2 + hi) * 8];
        ctxa[ch] = __builtin_amdgcn_mfma_f32_32x32x16_bf16(v1.v, pf1.v, ctxa[ch], 0, 0, 0);
      }
    }
    bar_lgkm();
  }
  const int col0 = nkt * KT;
  #pragma unroll 1
  for (int r = 0; r < 32; ++r) {
    float* zp = attn_out + ((size_t)bh * Qn + qbw + r) * Kn;
    for (int c4 = col0 + lane * 4; c4 < Kn; c4 += 256)
      *(f32x4*)(zp + c4) = (f32x4){0.f, 0.f, 0.f, 0.f};
  }
  float* cp = ctx_out + (((size_t)(b * Qn + qbw + l31)) * Hn + h) * Dn;
  #pragma unroll
  for (int ch = 0; ch < 4; ++ch)
    #pragma unroll
    for (int r4 = 0; r4 < 4; ++r4) {
      f32x4 o;
      #pragma unroll
      for (int rr = 0; rr < 4; ++rr) o[rr] = ctxa[ch][r4 * 4 + rr];
      *(f32x4*)(cp + ch * 32 + r4 * 8 + hi * 4) = o;
    }
}

extern "C" void kernel_launch(void* const* d_in, const int* in_sizes, int n_in,
                              void* d_out, int out_size, void* d_ws, size_t ws_size,
                              hipStream_t stream) {
  const float* qs   = (const float*)d_in[0];
  const float* ks   = (const float*)d_in[1];
  const float* vs   = (const float*)d_in[2];
  const int*   vlen = (const int*)d_in[3];
  float* ctx  = (float*)d_out;
  float* attn = ctx + (size_t)B_ * Qn * Hn * Dn;

  if (ws_size >= ((size_t)32 << 20)) {
    unsigned short* kws = (unsigned short*)d_ws;
    unsigned short* vws = kws + ((size_t)8 << 20);   // +16MB (in shorts)
    conv_kv<<<dim3(1536), 256, 0, stream>>>(ks, vs, vlen, kws, vws);
    attn_fwd<<<dim3((Qn / QT) * B_ * Hn), 256, 0, stream>>>(
        qs, vlen, (const char*)kws, (const char*)vws, ctx, attn);
  } else {
    attn_fwd_fb<<<dim3((Qn / QT) * B_ * Hn), 256, 0, stream>>>(qs, ks, vs, vlen, ctx, attn);
  }
}

// Round 21
// 183.065 us; speedup vs baseline: 1.0889x; 1.0889x over previous
//
#include <hip/hip_runtime.h>
#include <hip/hip_bf16.h>
#include <stdint.h>

#define B_ 2
#define Qn 2048
#define Kn 2048
#define Hn 16
#define Dn 128
#define QT 128     // q rows per block (4 waves x 32)
#define HD (Hn*Dn)

typedef __bf16 bf16x8 __attribute__((ext_vector_type(8)));
typedef __bf16 bf16x4 __attribute__((ext_vector_type(4)));
typedef float f32x4 __attribute__((ext_vector_type(4)));
typedef float f32x16 __attribute__((ext_vector_type(16)));
typedef unsigned short u16x8 __attribute__((ext_vector_type(8)));

union BF8 { __bf16 e[8]; bf16x8 v; };
union U16x8 { unsigned short u[8]; u16x8 v; };

#define SCALE 0.088388347648318447f            // 1/sqrt(128)
#define SCL2  (0.088388347648318447f * 1.4426950408889634f)  // SCALE*log2(e)

#if __has_builtin(__builtin_amdgcn_exp2f)
#define EXP2(x) __builtin_amdgcn_exp2f(x)
#else
#define EXP2(x) exp2f(x)
#endif

__device__ __forceinline__ bf16x4 cvt4(f32x4 a) {
  bf16x4 r;
  r[0] = (__bf16)a[0]; r[1] = (__bf16)a[1];
  r[2] = (__bf16)a[2]; r[3] = (__bf16)a[3];
  return r;
}

// ====================== fused prologue: K + V images (one launch) ======================
// K image[bh][t128]: [128 rows(keys)][16 slots of 16B], slot' = (slot+row)&15
// V image[bh][t64]:  [128 rows(d)][8 slots of 16B]; slot ds = chunk c=(ds-d)&7,
//   chunk c = keys base(c)+{0..3,8..11}, base(c)=(c>>2)*32+((c>>1)&1)*16+(c&1)*4
__global__ __launch_bounds__(256) void conv_kv(const float* __restrict__ ks,
                                               const float* __restrict__ vs,
                                               const int* __restrict__ vlen,
                                               unsigned short* __restrict__ kws,
                                               unsigned short* __restrict__ vws) {
  __shared__ unsigned short l[64 * 132];
  const int tid = threadIdx.x;
  if (blockIdx.x < 512) {
    const int blk = blockIdx.x;            // bh*16 + t
    const int bh = blk >> 4, t = blk & 15;
    const int b = bh >> 4, h = bh & 15;
    const int nkt = (vlen[b] + 63) >> 6;
    if (t * 2 >= nkt) return;
    const float* src = ks + ((size_t)(b * Kn + t * 128) * Hn + h) * Dn;
    unsigned short* dst = kws + (size_t)blk * 16384;
    #pragma unroll
    for (int i = 0; i < 8; ++i) {
      int idx = i * 256 + tid;
      int row = idx >> 4, sp = idx & 15;
      int slot = (sp - row) & 15;
      const float* s2 = src + (size_t)row * HD + slot * 8;
      f32x4 a0 = *(const f32x4*)s2;
      f32x4 a1 = *(const f32x4*)(s2 + 4);
      U16x8 o;
      *(bf16x4*)&o.u[0] = cvt4(a0);
      *(bf16x4*)&o.u[4] = cvt4(a1);
      *(u16x8*)(dst + (size_t)idx * 8) = o.v;
    }
  } else {
    const int blk = blockIdx.x - 512;      // bh*32 + t
    const int bh = blk >> 5, t = blk & 31;
    const int b = bh >> 4, h = bh & 15;
    const int nkt = (vlen[b] + 63) >> 6;
    if (t >= nkt) return;
    const float* src = vs + ((size_t)(b * Kn + t * 64) * Hn + h) * Dn;
    #pragma unroll
    for (int i = 0; i < 8; ++i) {
      int idx = i * 256 + tid;
      int k = idx >> 5, dc = idx & 31;
      f32x4 a = *(const f32x4*)(src + (size_t)k * HD + dc * 4);
      *(bf16x4*)&l[k * 132 + dc * 4] = cvt4(a);
    }
    __syncthreads();
    unsigned short* dst = vws + (size_t)blk * 8192;
    #pragma unroll
    for (int i = 0; i < 4; ++i) {
      int idx = i * 256 + tid;
      int d = idx >> 3, ds = idx & 7;
      int c = (ds - d) & 7;
      int kb = ((c >> 2) * 32) + (((c >> 1) & 1) * 16) + ((c & 1) * 4);
      U16x8 o;
      #pragma unroll
      for (int j = 0; j < 4; ++j) {
        o.u[j]     = l[(kb + j) * 132 + d];
        o.u[4 + j] = l[(kb + 8 + j) * 132 + d];
      }
      *(u16x8*)(dst + (size_t)idx * 8) = o.v;
    }
  }
}

// ====================== main kernel ======================
__device__ __forceinline__ void dma16(const void* g, void* l) {
  __builtin_amdgcn_global_load_lds((const __attribute__((address_space(1))) void*)g,
                                   (__attribute__((address_space(3))) void*)l, 16, 0, 0);
}
__device__ __forceinline__ void dma_tile(const char* gsrc, char* lds, int tid, int n4k) {
  const int off  = tid * 16;
  const int woff = (tid & 192) * 16;   // wave-uniform LDS base part
  #pragma unroll
  for (int i = 0; i < n4k; ++i)
    dma16(gsrc + i * 4096 + off, lds + i * 4096 + woff);
}

#define WAIT0BAR do { \
  asm volatile("s_waitcnt vmcnt(0)" ::: "memory"); \
  __builtin_amdgcn_s_barrier(); \
  __builtin_amdgcn_sched_barrier(0); } while (0)

// counted: completes the 8 oldest (prefetch loads), leaves <=16 youngest (attn stores)
#define WAIT16BAR do { \
  asm volatile("s_waitcnt vmcnt(16)" ::: "memory"); \
  __builtin_amdgcn_s_barrier(); \
  __builtin_amdgcn_sched_barrier(0); } while (0)

__global__ __launch_bounds__(256, 2) void attn_fwd(
    const float* __restrict__ qs, const int* __restrict__ vlen,
    const char* __restrict__ kimg, const char* __restrict__ vimg,
    float* __restrict__ ctx_out, float* __restrict__ attn_out)
{
  __shared__ __align__(16) char smraw[65536];
  // pass 1: K dbuf 2x16KB @0, V dbuf 2x16KB @32768. pass 2: K dbuf 2x32KB @0.

  const int tid = threadIdx.x, wave = tid >> 6, lane = tid & 63;
  const int l31 = lane & 31, hi = lane >> 5;

  // R18 decode: xcd pins bh-group, batches mixed per XCD
  const int L   = blockIdx.x;
  const int xcd = L & 7;
  const int i5  = L >> 3;
  const int bh  = ((i5 & 3) << 3) + xcd;
  const int qt  = i5 >> 2;
  const int b   = bh >> 4, h = bh & 15;
  const int vl  = vlen[b];
  const int qbw = qt * QT + wave * 32;

  // per-lane ds_read addresses (rotation: row&15 == l31&15 since m*32 = 0 mod 16)
  int vaddrK[8], vaddrV[4];
  #pragma unroll
  for (int s = 0; s < 8; ++s)
    vaddrK[s] = l31 * 256 + (((2 * s + hi + l31) & 15) << 4);
  #pragma unroll
  for (int jj = 0; jj < 4; ++jj)
    vaddrV[jj] = l31 * 128 + ((((hi + 2 * jj) + l31) & 7) << 4);

  // Q fragments pre-scaled by SCALE*log2e
  BF8 qf[8];
  {
    const float* qrow = qs + (((size_t)(b * Qn + qbw + l31)) * Hn + h) * Dn;
    #pragma unroll
    for (int s = 0; s < 8; ++s) {
      int d0 = s * 16 + hi * 8;
      f32x4 a0 = *(const f32x4*)(qrow + d0);
      f32x4 a1 = *(const f32x4*)(qrow + d0 + 4);
      #pragma unroll
      for (int jj = 0; jj < 4; ++jj) {
        qf[s].e[jj]     = (__bf16)(a0[jj] * SCL2);
        qf[s].e[4 + jj] = (__bf16)(a1[jj] * SCL2);
      }
    }
  }

  const char* kimg_bh = kimg + ((size_t)(bh * 16) << 15);
  const char* vimg_bh = vimg + ((size_t)(bh * 32) << 14);

  const int nkt  = (vl + 63) >> 6;      // 64-key tiles (pass 1)
  const int nkt2 = (vl + 127) >> 7;     // 128-key tiles (pass 2)
  const int col0 = nkt * 64;            // attn cols >= col0 are exactly 0

  // ====== pass 1: QK -> exp (unnormalized) -> row sums + PV accumulate ======
  // No global stores inside this loop -> vmcnt(0) waits on the 8 DMA loads only.
  f32x4 rsv = {0.f, 0.f, 0.f, 0.f};
  f32x16 ctxa[4];
  #pragma unroll
  for (int ch = 0; ch < 4; ++ch)
    #pragma unroll
    for (int i = 0; i < 16; ++i) ctxa[ch][i] = 0.f;

  {
    const bool hasb = (vl & 63) != 0;
    dma_tile(kimg_bh, smraw, tid, 4);              // K half-image 0
    dma_tile(vimg_bh, smraw + 32768, tid, 4);      // V tile 0
    WAIT0BAR;
    for (int t = 0; t < nkt; ++t) {
      const int cur = t & 1;
      if (t + 1 < nkt) {
        const int tn = t + 1;
        dma_tile(kimg_bh + ((size_t)(tn >> 1) << 15) + ((size_t)(tn & 1) << 14),
                 smraw + ((cur ^ 1) << 14), tid, 4);
        dma_tile(vimg_bh + ((size_t)tn << 14), smraw + 32768 + ((cur ^ 1) << 14), tid, 4);
      }
      const bool mb = hasb && (t == nkt - 1);
      const char* kb_l = smraw + (cur << 14);
      const char* vb_l = smraw + 32768 + (cur << 14);
      #pragma unroll
      for (int m = 0; m < 2; ++m) {
        f32x16 acc;
        #pragma unroll
        for (int i = 0; i < 16; ++i) acc[i] = 0.f;
        #pragma unroll
        for (int s = 0; s < 8; ++s) {
          BF8 kf; kf.v = *(const bf16x8*)(kb_l + m * 8192 + vaddrK[s]);
          acc = __builtin_amdgcn_mfma_f32_32x32x16_bf16(kf.v, qf[s].v, acc, 0, 0, 0);
        }
        const int kb0 = t * 64 + m * 32;
        BF8 pf0, pf1;
        #pragma unroll
        for (int r4 = 0; r4 < 4; ++r4) {
          #pragma unroll
          for (int rr = 0; rr < 4; ++rr) {
            float e;
            if (!mb) e = EXP2(acc[r4 * 4 + rr]);
            else {
              int key = kb0 + r4 * 8 + hi * 4 + rr;
              e = (key < vl) ? EXP2(acc[r4 * 4 + rr]) : 0.f;
            }
            rsv[rr] += e;
            if (r4 < 2) pf0.e[r4 * 4 + rr] = (__bf16)e;
            else        pf1.e[(r4 - 2) * 4 + rr] = (__bf16)e;
          }
        }
        #pragma unroll
        for (int ch = 0; ch < 4; ++ch) {
          BF8 v0; v0.v = *(const bf16x8*)(vb_l + ch * 4096 + vaddrV[2 * m]);
          ctxa[ch] = __builtin_amdgcn_mfma_f32_32x32x16_bf16(v0.v, pf0.v, ctxa[ch], 0, 0, 0);
          BF8 v1; v1.v = *(const bf16x8*)(vb_l + ch * 4096 + vaddrV[2 * m + 1]);
          ctxa[ch] = __builtin_amdgcn_mfma_f32_32x32x16_bf16(v1.v, pf1.v, ctxa[ch], 0, 0, 0);
        }
      }
      WAIT0BAR;
    }
  }
  float rs = (rsv[0] + rsv[1]) + (rsv[2] + rsv[3]);
  rs += __shfl_xor(rs, 32);
  const float inv = 1.0f / rs;   // row sum for q-row (qbw + l31)

  // ====== zero-fill masked attn columns: fire-and-forget burst (regular stores,
  // merge in L2; drained once by pass 2's first barrier) ======
  {
    const f32x4 z4 = {0.f, 0.f, 0.f, 0.f};
    #pragma unroll 1
    for (int r = 0; r < 32; ++r) {
      float* zp = attn_out + ((size_t)bh * Qn + qbw + r) * Kn;
      for (int c4 = col0 + lane * 4; c4 < Kn; c4 += 256)
        *(f32x4*)(zp + c4) = z4;
    }
  }

  // ====== pass 2: lean QK -> exp*inv -> attn store (KT=128, K-only dbuf) ======
  {
    const bool hasb2 = (vl & 127) != 0;
    dma_tile(kimg_bh, smraw, tid, 8);
    WAIT0BAR;                            // drains zero burst + initial dma (once)
    float* rowp = attn_out + ((size_t)bh * Qn + qbw + l31) * Kn;
    for (int t = 0; t < nkt2; ++t) {
      const int cur = t & 1;
      if (t + 1 < nkt2)
        dma_tile(kimg_bh + ((size_t)(t + 1) << 15), smraw + ((cur ^ 1) << 15), tid, 8);
      const bool mb = hasb2 && (t == nkt2 - 1);
      const char* kb_l = smraw + (cur << 15);
      #pragma unroll
      for (int m = 0; m < 4; ++m) {
        f32x16 acc;
        #pragma unroll
        for (int i = 0; i < 16; ++i) acc[i] = 0.f;
        #pragma unroll
        for (int s = 0; s < 8; ++s) {
          BF8 kf; kf.v = *(const bf16x8*)(kb_l + m * 8192 + vaddrK[s]);
          acc = __builtin_amdgcn_mfma_f32_32x32x16_bf16(kf.v, qf[s].v, acc, 0, 0, 0);
        }
        const int kb0 = t * 128 + m * 32;
        #pragma unroll
        for (int r4 = 0; r4 < 4; ++r4) {
          f32x4 p;
          if (!mb) {
            #pragma unroll
            for (int rr = 0; rr < 4; ++rr) p[rr] = EXP2(acc[r4 * 4 + rr]) * inv;
          } else {
            #pragma unroll
            for (int rr = 0; rr < 4; ++rr) {
              int key = kb0 + r4 * 8 + hi * 4 + rr;
              p[rr] = (key < vl) ? EXP2(acc[r4 * 4 + rr]) * inv : 0.f;
            }
          }
          *(f32x4*)(rowp + kb0 + r4 * 8 + hi * 4) = p;
        }
      }
      WAIT16BAR;   // 8 prefetch loads complete; attn stores stay in flight
    }
  }

  // epilogue: ctx[q=l31][d = ch*32 + r4*8 + hi*4 + rr] = ctxa * inv
  float* cp = ctx_out + (((size_t)(b * Qn + qbw + l31)) * Hn + h) * Dn;
  #pragma unroll
  for (int ch = 0; ch < 4; ++ch)
    #pragma unroll
    for (int r4 = 0; r4 < 4; ++r4) {
      f32x4 o;
      #pragma unroll
      for (int rr = 0; rr < 4; ++rr) o[rr] = ctxa[ch][r4 * 4 + rr] * inv;
      *(f32x4*)(cp + ch * 32 + r4 * 8 + hi * 4) = o;
    }
}

// ====================== fallback (R13-based, proven): used only if ws < 32MB ======================
#define KT 64
#define KT1 128
#define KROW 132
#define VROW 72
struct SMp2f { unsigned short K[2][KT][KROW]; unsigned short V[2][Dn][VROW]; };
union SMuf { SMp2f p2; unsigned short K1[2][KT1][KROW]; };

__device__ __forceinline__ void bar_lgkm() {
  asm volatile("s_waitcnt lgkmcnt(0)" ::: "memory");
  __builtin_amdgcn_s_barrier();
  __builtin_amdgcn_sched_barrier(0);
}
__device__ __forceinline__ void fb_stage_k64(const float* kb, unsigned short (*dst)[KROW], int tid) {
  #pragma unroll
  for (int ii = 0; ii < 8; ++ii) {
    int chunk = ii * 256 + tid;
    int row = chunk >> 5, cv = chunk & 31;
    f32x4 a = *(const f32x4*)(kb + (size_t)row * HD + cv * 4);
    *(bf16x4*)&dst[row][cv * 4] = cvt4(a);
  }
}
__device__ __forceinline__ void fb_stage_k128(const float* kb, unsigned short (*dst)[KROW], int tid) {
  #pragma unroll
  for (int ii = 0; ii < 16; ++ii) {
    int chunk = ii * 256 + tid;
    int row = chunk >> 5, cv = chunk & 31;
    f32x4 a = *(const f32x4*)(kb + (size_t)row * HD + cv * 4);
    *(bf16x4*)&dst[row][cv * 4] = cvt4(a);
  }
}
__device__ __forceinline__ void fb_stage_v64(const float* vb, unsigned short (*dst)[VROW], int tid) {
  int d = tid & 127, t0 = tid >> 7;
  const float* colp = vb + d;
  #pragma unroll
  for (int rr = 0; rr < 4; ++rr) {
    int idx = rr * 2 + t0;
    int base = (idx >> 2) * 32 + ((idx >> 1) & 1) * 16 + (idx & 1) * 4;
    BF8 t;
    #pragma unroll
    for (int jj = 0; jj < 4; ++jj) {
      t.e[jj]     = (__bf16)colp[(size_t)(base + jj) * HD];
      t.e[4 + jj] = (__bf16)colp[(size_t)(base + 8 + jj) * HD];
    }
    *(bf16x8*)&dst[d][idx * 8] = t.v;
  }
}
__global__ __launch_bounds__(256, 2) void attn_fwd_fb(
    const float* __restrict__ qs, const float* __restrict__ ks,
    const float* __restrict__ vs, const int* __restrict__ vlen,
    float* __restrict__ ctx_out, float* __restrict__ attn_out)
{
  __shared__ __align__(16) SMuf sm;
  const int tid = threadIdx.x, wave = tid >> 6, lane = tid & 63;
  const int l31 = lane & 31, hi = lane >> 5;
  const int L = blockIdx.x, xcd = L & 7, i5 = L >> 3;
  const int bh = ((i5 & 3) << 3) + xcd, qt = i5 >> 2;
  const int b = bh >> 4, h = bh & 15;
  const int vl = vlen[b];
  const int qbw = qt * QT + wave * 32;
  BF8 qf[8];
  {
    const float* qrow = qs + (((size_t)(b * Qn + qbw + l31)) * Hn + h) * Dn;
    #pragma unroll
    for (int s = 0; s < 8; ++s) {
      int d0 = s * 16 + hi * 8;
      f32x4 a0 = *(const f32x4*)(qrow + d0);
      f32x4 a1 = *(const f32x4*)(qrow + d0 + 4);
      #pragma unroll
      for (int jj = 0; jj < 4; ++jj) {
        qf[s].e[jj] = (__bf16)(a0[jj] * SCL2);
        qf[s].e[4 + jj] = (__bf16)(a1[jj] * SCL2);
      }
    }
  }
  const float* kbase = ks + ((size_t)b * Kn * Hn + h) * Dn;
  const float* vbase = vs + ((size_t)b * Kn * Hn + h) * Dn;
  f32x4 rsv = {0.f, 0.f, 0.f, 0.f};
  {
    const int nkt1 = (vl + KT1 - 1) / KT1;
    const bool hasb1 = (vl & (KT1 - 1)) != 0;
    fb_stage_k128(kbase, sm.K1[0], tid);
    bar_lgkm();
    for (int t = 0; t < nkt1; ++t) {
      const int cur = t & 1;
      if (t + 1 < nkt1) fb_stage_k128(kbase + (size_t)(t + 1) * KT1 * HD, sm.K1[cur ^ 1], tid);
      const bool mb = hasb1 && (t == nkt1 - 1);
      #pragma unroll
      for (int m = 0; m < 4; ++m) {
        f32x16 acc;
        #pragma unroll
        for (int i = 0; i < 16; ++i) acc[i] = 0.f;
        #pragma unroll
        for (int s = 0; s < 8; ++s) {
          BF8 kf; kf.v = *(const bf16x8*)&sm.K1[cur][m * 32 + l31][s * 16 + hi * 8];
          acc = __builtin_amdgcn_mfma_f32_32x32x16_bf16(kf.v, qf[s].v, acc, 0, 0, 0);
        }
        if (!mb) {
          #pragma unroll
          for (int reg = 0; reg < 16; ++reg) rsv[reg & 3] += EXP2(acc[reg]);
        } else {
          const int kb0 = t * KT1 + m * 32 + hi * 4;
          #pragma unroll
          for (int reg = 0; reg < 16; ++reg) {
            int key = kb0 + (reg & 3) + 8 * (reg >> 2);
            rsv[reg & 3] += (key < vl) ? EXP2(acc[reg]) : 0.f;
          }
        }
      }
      bar_lgkm();
    }
  }
  float rs = (rsv[0] + rsv[1]) + (rsv[2] + rsv[3]);
  rs += __shfl_xor(rs, 32);
  const float inv = 1.0f / rs;
  f32x16 ctxa[4];
  #pragma unroll
  for (int ch = 0; ch < 4; ++ch)
    #pragma unroll
    for (int i = 0; i < 16; ++i) ctxa[ch][i] = 0.f;
  const int nkt = (vl + KT - 1) / KT;
  const bool hasb2 = (vl & (KT - 1)) != 0;
  fb_stage_k64(kbase, sm.p2.K[0], tid);
  fb_stage_v64(vbase, sm.p2.V[0], tid);
  bar_lgkm();
  float* rowp = attn_out + ((size_t)bh * Qn + qbw + l31) * Kn;
  for (int t = 0; t < nkt; ++t) {
    const int cur = t & 1;
    if (t + 1 < nkt) {
      fb_stage_k64(kbase + (size_t)(t + 1) * KT * HD, sm.p2.K[cur ^ 1], tid);
      fb_stage_v64(vbase + (size_t)(t + 1) * KT * HD, sm.p2.V[cur ^ 1], tid);
    }
    const bool mb = hasb2 && (t == nkt - 1);
    #pragma unroll
    for (int m = 0; m < 2; ++m) {
      f32x16 acc;
      #pragma unroll
      for (int i = 0; i < 16; ++i) acc[i] = 0.f;
      #pragma unroll
      for (int s = 0; s < 8; ++s) {
        BF8 kf; kf.v = *(const bf16x8*)&sm.p2.K[cur][m * 32 + l31][s * 16 + hi * 8];
        acc = __builtin_amdgcn_mfma_f32_32x32x16_bf16(kf.v, qf[s].v, acc, 0, 0, 0);
      }
      const int kb0 = t * KT + m * 32;
      BF8 pf0, pf1;
      #pragma unroll
      for (int r4 = 0; r4 < 4; ++r4) {
        f32x4 p;
        if (!mb) {
          #pragma unroll
          for (int rr = 0; rr < 4; ++rr) p[rr] = EXP2(acc[r4 * 4 + rr]) * inv;
        } else {
          #pragma unroll
          for (int rr = 0; rr < 4; ++rr) {
            int key = kb0 + r4 * 8 + hi * 4 + rr;
            p[rr] = (key < vl) ? EXP2(acc[r4 * 4 + rr]) * inv : 0.f;
          }
        }
        #pragma unroll
        for (int rr = 0; rr < 4; ++rr) {
          if (r4 < 2) pf0.e[r4 * 4 + rr] = (__bf16)p[rr];
          else        pf1.e[(r4 - 2) * 4 + rr] = (__bf16)p[rr];
        }
        *(f32x4*)(rowp + kb0 + r4 * 8 + hi * 4) = p;
      }
      #pragma unroll
      for (int ch = 0; ch < 4; ++ch) {
        BF8 v0; v0.v = *(const bf16x8*)&sm.p2.V[cur][ch * 32 + l31][(m * 4 + hi) * 8];
        ctxa[ch] = __builtin_amdgcn_mfma_f32_32x32x16_bf16(v0.v, pf0.v, ctxa[ch], 0, 0, 0);
        BF8 v1; v1.v = *(const bf16x8*)&sm.p2.V[cur][ch * 32 + l31][(m * 4 + 2 + hi) * 8];
        ctxa[ch] = __builtin_amdgcn_mfma_f32_32x32x16_bf16(v1.v, pf1.v, ctxa[ch], 0, 0, 0);
      }
    }
    bar_lgkm();
  }
  const int col0 = nkt * KT;
  #pragma unroll 1
  for (int r = 0; r < 32; ++r) {
    float* zp = attn_out + ((size_t)bh * Qn + qbw + r) * Kn;
    for (int c4 = col0 + lane * 4; c4 < Kn; c4 += 256)
      *(f32x4*)(zp + c4) = (f32x4){0.f, 0.f, 0.f, 0.f};
  }
  float* cp = ctx_out + (((size_t)(b * Qn + qbw + l31)) * Hn + h) * Dn;
  #pragma unroll
  for (int ch = 0; ch < 4; ++ch)
    #pragma unroll
    for (int r4 = 0; r4 < 4; ++r4) {
      f32x4 o;
      #pragma unroll
      for (int rr = 0; rr < 4; ++rr) o[rr] = ctxa[ch][r4 * 4 + rr];
      *(f32x4*)(cp + ch * 32 + r4 * 8 + hi * 4) = o;
    }
}

extern "C" void kernel_launch(void* const* d_in, const int* in_sizes, int n_in,
                              void* d_out, int out_size, void* d_ws, size_t ws_size,
                              hipStream_t stream) {
  const float* qs   = (const float*)d_in[0];
  const float* ks   = (const float*)d_in[1];
  const float* vs   = (const float*)d_in[2];
  const int*   vlen = (const int*)d_in[3];
  float* ctx  = (float*)d_out;
  float* attn = ctx + (size_t)B_ * Qn * Hn * Dn;

  if (ws_size >= ((size_t)32 << 20)) {
    unsigned short* kws = (unsigned short*)d_ws;
    unsigned short* vws = kws + ((size_t)8 << 20);   // +16MB (in shorts)
    conv_kv<<<dim3(1536), 256, 0, stream>>>(ks, vs, vlen, kws, vws);
    attn_fwd<<<dim3((Qn / QT) * B_ * Hn), 256, 0, stream>>>(
        qs, vlen, (const char*)kws, (const char*)vws, ctx, attn);
  } else {
    attn_fwd_fb<<<dim3((Qn / QT) * B_ * Hn), 256, 0, stream>>>(qs, ks, vs, vlen, ctx, attn);
  }
}